// Round 1
// baseline (255.799 us; speedup 1.0000x reference)
//
#include <hip/hip_runtime.h>
#include <stdint.h>

#define HEADS 12
#define DIMH  64
#define DIM   768
#define INNER 768
#define N3    2304      // 3*INNER
#define SEQ   2048
#define BATCH 2
#define ATT_SCALE 0.125f
#define NEGV  -1e9f

typedef _Float16 f16;
typedef _Float16 half8 __attribute__((ext_vector_type(8)));
typedef float    f32x4 __attribute__((ext_vector_type(4)));

typedef __attribute__((address_space(1))) const void gv_t;
typedef __attribute__((address_space(3))) void       sv_t;

__device__ __forceinline__ void gload16(const void* g, void* l) {
  // async global->LDS, 16B per lane, LDS dest = wave-uniform base + lane*16
  __builtin_amdgcn_global_load_lds((gv_t*)g, (sv_t*)l, 16, 0, 0);
}

// ---------------- LayerNorm: x f32 [4096][768] -> xn f16 ----------------
__global__ __launch_bounds__(256) void ln_kernel(const float* __restrict__ x,
    const float* __restrict__ gamma, const float* __restrict__ beta,
    f16* __restrict__ xn) {
  __shared__ float red[8];
  const int row = blockIdx.x;
  const int tid = threadIdx.x;
  const float* xr = x + (size_t)row * DIM;
  float v0 = xr[tid], v1 = xr[tid + 256], v2 = xr[tid + 512];
  float s = v0 + v1 + v2;
#pragma unroll
  for (int o = 32; o >= 1; o >>= 1) s += __shfl_xor(s, o);
  if ((tid & 63) == 0) red[tid >> 6] = s;
  __syncthreads();
  const float mu = (red[0] + red[1] + red[2] + red[3]) * (1.0f / DIM);
  float d0 = v0 - mu, d1 = v1 - mu, d2 = v2 - mu;
  float q = d0 * d0 + d1 * d1 + d2 * d2;
#pragma unroll
  for (int o = 32; o >= 1; o >>= 1) q += __shfl_xor(q, o);
  if ((tid & 63) == 0) red[4 + (tid >> 6)] = q;
  __syncthreads();
  const float var = (red[4] + red[5] + red[6] + red[7]) * (1.0f / DIM);
  const float rs = rsqrtf(var + 1e-5f);
  f16* xo = xn + (size_t)row * DIM;
  xo[tid]       = (f16)(d0 * rs * gamma[tid]       + beta[tid]);
  xo[tid + 256] = (f16)(d1 * rs * gamma[tid + 256] + beta[tid + 256]);
  xo[tid + 512] = (f16)(d2 * rs * gamma[tid + 512] + beta[tid + 512]);
}

// ------------- transpose f32 [R][C] -> f16 [C][R] (weights) -------------
__global__ __launch_bounds__(256) void transpose_f32f16(const float* __restrict__ in,
    f16* __restrict__ outp, int R, int C) {
  __shared__ float t[32][33];
  const int c0 = blockIdx.x * 32, r0 = blockIdx.y * 32;
  const int tx = threadIdx.x & 31, ty = threadIdx.x >> 5;  // ty 0..7
#pragma unroll
  for (int i = 0; i < 32; i += 8)
    t[ty + i][tx] = in[(size_t)(r0 + ty + i) * C + c0 + tx];
  __syncthreads();
#pragma unroll
  for (int i = 0; i < 32; i += 8)
    outp[(size_t)(c0 + ty + i) * R + r0 + tx] = (f16)t[tx][ty + i];
}

// ------- V transpose: qkv f16 [4096][2304] -> vt f16 [24*64][2048] -------
__global__ __launch_bounds__(256) void vt_kernel(const f16* __restrict__ qkvb,
                                                 f16* __restrict__ vtb) {
  __shared__ f16 t[64][68];
  const int t0 = blockIdx.x * 64, bh = blockIdx.y;
  const int b = bh / HEADS, h = bh % HEADS;
  const int tx = threadIdx.x & 63, ty = threadIdx.x >> 6;  // ty 0..3
#pragma unroll
  for (int i = 0; i < 64; i += 4)
    t[ty + i][tx] = qkvb[(size_t)(b * SEQ + t0 + ty + i) * N3 + 2 * INNER + h * DIMH + tx];
  __syncthreads();
#pragma unroll
  for (int i = 0; i < 64; i += 4)
    vtb[(size_t)(bh * DIMH + ty + i) * SEQ + t0 + tx] = t[tx][ty + i];
}

// ---------------- GEMM: C[M][N] = A[M][K] * Bt[N][K]^T  (m97 structure) ----------------
template <bool OUTF16>
__global__ __launch_bounds__(256) void gemm_f16(const f16* __restrict__ A,
    const f16* __restrict__ Bt, void* __restrict__ Cout, int M, int N, int K) {
  __shared__ f16 As[128 * 64];
  __shared__ f16 Bs[128 * 64];
  const int tid = threadIdx.x, l = tid & 63, w = tid >> 6;
  const int wm = w >> 1, wn = w & 1;
  const int lq = l & 15, g = l >> 4;
  const int m0 = blockIdx.x * 128, n0 = blockIdx.y * 128;
  f32x4 acc[4][4] = {};
  for (int kt = 0; kt < K; kt += 64) {
    __syncthreads();
#pragma unroll
    for (int i = 0; i < 4; i++) {
      const int row = i * 32 + w * 8 + (l >> 3);
      gload16((const char*)(A + (size_t)(m0 + row) * K + kt) + (l & 7) * 16,
              (char*)As + (i * 32 + w * 8) * 128);
      gload16((const char*)(Bt + (size_t)(n0 + row) * K + kt) + (l & 7) * 16,
              (char*)Bs + (i * 32 + w * 8) * 128);
    }
    __syncthreads();
#pragma unroll
    for (int kk = 0; kk < 2; kk++) {
      half8 a[4], bfr[4];
#pragma unroll
      for (int fm = 0; fm < 4; fm++)
        a[fm] = *(const half8*)(As + (wm * 64 + fm * 16 + lq) * 64 + kk * 32 + g * 8);
#pragma unroll
      for (int fn = 0; fn < 4; fn++)
        bfr[fn] = *(const half8*)(Bs + (wn * 64 + fn * 16 + lq) * 64 + kk * 32 + g * 8);
#pragma unroll
      for (int fm = 0; fm < 4; fm++)
#pragma unroll
        for (int fn = 0; fn < 4; fn++)
          acc[fm][fn] = __builtin_amdgcn_mfma_f32_16x16x32_f16(a[fm], bfr[fn], acc[fm][fn], 0, 0, 0);
    }
  }
#pragma unroll
  for (int fm = 0; fm < 4; fm++)
#pragma unroll
    for (int fn = 0; fn < 4; fn++)
#pragma unroll
      for (int r = 0; r < 4; r++) {
        const int row = m0 + wm * 64 + fm * 16 + g * 4 + r;
        const int col = n0 + wn * 64 + fn * 16 + lq;
        const float v = acc[fm][fn][r];
        if (OUTF16) ((f16*)Cout)[(size_t)row * N + col] = (f16)v;
        else        ((float*)Cout)[(size_t)row * N + col] = v;
      }
}

// ---------------- fused attention (2-pass, swapped-QK^T, 64 q-rows/block) ----------------
__global__ __launch_bounds__(256) void attn_kernel(
    const f16* __restrict__ qkv, const f16* __restrict__ vt,
    const float* __restrict__ con, const int* __restrict__ labels,
    float* __restrict__ attn, f16* __restrict__ hout) {
  __shared__ f16 Ks[128 * 64];    // [key][d]   swizzled rows (128B)
  __shared__ f16 VTs[64 * 128];   // [d][key]   swizzled rows (256B)
  __shared__ f16 Ps[64 * 128];    // [q][key]   swizzled rows (256B)
  __shared__ float padf[128];

  const int tid = threadIdx.x;
  const int l = tid & 63, w = tid >> 6;
  const int lq = l & 15, g = l >> 4;
  const int bh = blockIdx.y, b = bh / HEADS, h = bh % HEADS;
  const int q0 = blockIdx.x * 64;
  const int qrow = q0 + w * 16 + lq;

  // Q fragments (B-operand of swapped QK^T; also A-layout compatible)
  const f16* qptr = qkv + (size_t)(b * SEQ + qrow) * N3 + h * DIMH + g * 8;
  const half8 qf0 = *(const half8*)(qptr);
  const half8 qf1 = *(const half8*)(qptr + 32);
  const float* conrow = con + (size_t)(b * SEQ + qrow) * SEQ;
  const int* labr = labels + b * SEQ;
  const int sw = (lq & 7) << 4;

  float ssum = 0.f;
  // ================= pass 1: denominator =================
  for (int kt = 0; kt < SEQ; kt += 128) {
    __syncthreads();
#pragma unroll
    for (int i = 0; i < 4; i++) {
      const int row = i * 32 + w * 8 + (l >> 3);
      const int cb = ((l & 7) * 16) ^ ((row & 7) << 4);   // pre-swizzled source
      gload16((const char*)(qkv + (size_t)(b * SEQ + kt + row) * N3 + INNER + h * DIMH) + cb,
              (char*)Ks + (i * 32 + w * 8) * 128);
    }
    if (tid < 128) padf[tid] = (labr[kt + tid] == 0) ? 1.f : 0.f;
    __syncthreads();
#pragma unroll
    for (int f = 0; f < 8; f++) {
      f32x4 acc = {};
      const char* kb = (const char*)Ks + (f * 16 + lq) * 128;
      const half8 ka0 = *(const half8*)(kb + ((g * 16) ^ sw));
      const half8 ka1 = *(const half8*)(kb + ((64 + g * 16) ^ sw));
      acc = __builtin_amdgcn_mfma_f32_16x16x32_f16(ka0, qf0, acc, 0, 0, 0);
      acc = __builtin_amdgcn_mfma_f32_16x16x32_f16(ka1, qf1, acc, 0, 0, 0);
      const int keyb = f * 16 + g * 4;
      const float4 c4 = *(const float4*)(conrow + kt + keyb);
      const float c4a[4] = {c4.x, c4.y, c4.z, c4.w};
#pragma unroll
      for (int r = 0; r < 4; r++) {
        const float sv = acc[r] * ATT_SCALE;
        const float p = padf[keyb + r];
        float lg = sv + p * (NEGV - sv);
        lg = lg + lg * c4a[r];
        lg = fminf(lg, 80.f);
        ssum += __expf(lg);
      }
    }
  }
  ssum += __shfl_xor(ssum, 16);
  ssum += __shfl_xor(ssum, 32);
  const float inv_s = 1.0f / ssum;

  // ================= pass 2: attn out + PV =================
  f32x4 oacc[4] = {};
  for (int kt = 0; kt < SEQ; kt += 128) {
    __syncthreads();
#pragma unroll
    for (int i = 0; i < 4; i++) {
      const int row = i * 32 + w * 8 + (l >> 3);
      const int cb = ((l & 7) * 16) ^ ((row & 7) << 4);
      gload16((const char*)(qkv + (size_t)(b * SEQ + kt + row) * N3 + INNER + h * DIMH) + cb,
              (char*)Ks + (i * 32 + w * 8) * 128);
    }
#pragma unroll
    for (int i = 0; i < 4; i++) {
      const int drow = i * 16 + w * 4 + (l >> 4);
      const int cb = ((l & 15) * 16) ^ ((drow & 7) << 4);
      gload16((const char*)(vt + (size_t)(bh * DIMH + drow) * SEQ + kt) + cb,
              (char*)VTs + (i * 16 + w * 4) * 256);
    }
    if (tid < 128) padf[tid] = (labr[kt + tid] == 0) ? 1.f : 0.f;
    __syncthreads();
    const int q_l = w * 16 + lq;
    const int psw = (q_l & 7) << 4;
#pragma unroll
    for (int f = 0; f < 8; f++) {
      f32x4 acc = {};
      const char* kb = (const char*)Ks + (f * 16 + lq) * 128;
      const half8 ka0 = *(const half8*)(kb + ((g * 16) ^ sw));
      const half8 ka1 = *(const half8*)(kb + ((64 + g * 16) ^ sw));
      acc = __builtin_amdgcn_mfma_f32_16x16x32_f16(ka0, qf0, acc, 0, 0, 0);
      acc = __builtin_amdgcn_mfma_f32_16x16x32_f16(ka1, qf1, acc, 0, 0, 0);
      const int keyb = f * 16 + g * 4;
      const float4 c4 = *(const float4*)(conrow + kt + keyb);
      const float c4a[4] = {c4.x, c4.y, c4.z, c4.w};
      union { f16 hh[4]; unsigned long long u; } pk;
#pragma unroll
      for (int r = 0; r < 4; r++) {
        const float sv = acc[r] * ATT_SCALE;
        const float p = padf[keyb + r];
        float lg = sv + p * (NEGV - sv);
        lg = lg + lg * c4a[r];
        lg = fminf(lg, 80.f);
        pk.hh[r] = (f16)(__expf(lg) * inv_s);
      }
      *(unsigned long long*)((char*)Ps + ((q_l * 256 + keyb * 2) ^ psw)) = pk.u;
    }
    __syncthreads();
    // coalesced attn f32 output via Ps staging
    {
      const int tq = tid >> 4, tk = (tid & 15) * 8;
#pragma unroll
      for (int i = 0; i < 4; i++) {
        const int qr = i * 16 + tq;
        const half8 pv = *(const half8*)((const char*)Ps + ((qr * 256 + tk * 2) ^ ((qr & 7) << 4)));
        float* ap = attn + ((size_t)(bh * SEQ + q0 + qr) * SEQ + kt + tk);
        *(float4*)ap = make_float4((float)pv[0], (float)pv[1], (float)pv[2], (float)pv[3]);
        *(float4*)(ap + 4) = make_float4((float)pv[4], (float)pv[5], (float)pv[6], (float)pv[7]);
      }
    }
    // PV: oacc[q][d] += P[q][key] * V[key][d]
#pragma unroll
    for (int kk = 0; kk < 4; kk++) {
      const half8 pa = *(const half8*)((const char*)Ps + ((q_l * 256 + kk * 64 + g * 16) ^ psw));
#pragma unroll
      for (int n = 0; n < 4; n++) {
        const half8 vb = *(const half8*)((const char*)VTs +
                          (((n * 16 + lq) * 256 + kk * 64 + g * 16) ^ sw));
        oacc[n] = __builtin_amdgcn_mfma_f32_16x16x32_f16(pa, vb, oacc[n], 0, 0, 0);
      }
    }
  }
  // write h (heads-concat) f16
#pragma unroll
  for (int n = 0; n < 4; n++)
#pragma unroll
    for (int r = 0; r < 4; r++) {
      const int row = b * SEQ + q0 + w * 16 + g * 4 + r;
      hout[(size_t)row * INNER + h * DIMH + n * 16 + lq] = (f16)oacc[n][r];
    }
}

// ---------------------------------------------------------------------------
extern "C" void kernel_launch(void* const* d_in, const int* in_sizes, int n_in,
                              void* d_out, int out_size, void* d_ws, size_t ws_size,
                              hipStream_t stream) {
  const float* x      = (const float*)d_in[0];
  const int*   labels = (const int*)d_in[1];
  const float* con    = (const float*)d_in[2];
  const float* gamma  = (const float*)d_in[3];
  const float* beta   = (const float*)d_in[4];
  const float* w_qkv  = (const float*)d_in[5];
  const float* w_out  = (const float*)d_in[6];

  float* out  = (float*)d_out;
  float* attn = out + (size_t)BATCH * SEQ * DIM;

  char* ws = (char*)d_ws;
  // ws layout (f16 buffers); xn region is reused for h after QKV GEMM.
  f16* xn   = (f16*)(ws);                       //  6,291,456 B
  f16* wtq  = (f16*)(ws + 6291456);             //  3,538,944 B
  f16* wto  = (f16*)(ws + 9830400);             //  1,179,648 B
  f16* qkvb = (f16*)(ws + 11010048);            // 18,874,368 B
  f16* vtb  = (f16*)(ws + 29884416);            //  6,291,456 B  (end: 36,175,872)
  f16* hbuf = xn;                               // alias: xn dead after QKV GEMM

  transpose_f32f16<<<dim3(N3 / 32, DIM / 32), 256, 0, stream>>>(w_qkv, wtq, DIM, N3);
  transpose_f32f16<<<dim3(DIM / 32, DIM / 32), 256, 0, stream>>>(w_out, wto, DIM, DIM);
  ln_kernel<<<BATCH * SEQ, 256, 0, stream>>>(x, gamma, beta, xn);
  gemm_f16<true><<<dim3((BATCH * SEQ) / 128, N3 / 128), 256, 0, stream>>>(
      xn, wtq, qkvb, BATCH * SEQ, N3, DIM);
  vt_kernel<<<dim3(SEQ / 64, BATCH * HEADS), 256, 0, stream>>>(qkvb, vtb);
  attn_kernel<<<dim3(SEQ / 64, BATCH * HEADS), 256, 0, stream>>>(
      qkvb, vtb, con, labels, attn, hbuf);
  gemm_f16<false><<<dim3((BATCH * SEQ) / 128, DIM / 128), 256, 0, stream>>>(
      hbuf, wto, out, BATCH * SEQ, DIM, DIM);
}